// Round 1
// baseline (20247.287 us; speedup 1.0000x reference)
//
#include <hip/hip_runtime.h>
#include <stdint.h>

#define NSIZE   64
#define NPTS    8192
#define NTILE   64
#define NTILES  (NPTS / NTILE)       // 128
#define NBLOCKS (NSIZE * NTILES)     // 8192

struct Keys { uint32_t k0[5]; uint32_t k1[5]; };

// ---------------- threefry2x32, 20 rounds (JAX-compatible) ----------------
#define TF_ROUNDS_A(x0,x1) \
  x0 += x1; x1 = (x1<<13)|(x1>>19); x1 ^= x0; \
  x0 += x1; x1 = (x1<<15)|(x1>>17); x1 ^= x0; \
  x0 += x1; x1 = (x1<<26)|(x1>>6);  x1 ^= x0; \
  x0 += x1; x1 = (x1<<6) |(x1>>26); x1 ^= x0;
#define TF_ROUNDS_B(x0,x1) \
  x0 += x1; x1 = (x1<<17)|(x1>>15); x1 ^= x0; \
  x0 += x1; x1 = (x1<<29)|(x1>>3);  x1 ^= x0; \
  x0 += x1; x1 = (x1<<16)|(x1>>16); x1 ^= x0; \
  x0 += x1; x1 = (x1<<24)|(x1>>8);  x1 ^= x0;

__host__ __device__ inline void threefry2x32(uint32_t k0, uint32_t k1,
                                             uint32_t c0, uint32_t c1,
                                             uint32_t& o0, uint32_t& o1) {
  uint32_t k2 = k0 ^ k1 ^ 0x1BD11BDAu;
  uint32_t x0 = c0 + k0, x1 = c1 + k1;
  TF_ROUNDS_A(x0,x1) x0 += k1; x1 += k2 + 1u;
  TF_ROUNDS_B(x0,x1) x0 += k2; x1 += k0 + 2u;
  TF_ROUNDS_A(x0,x1) x0 += k0; x1 += k1 + 3u;
  TF_ROUNDS_B(x0,x1) x0 += k1; x1 += k2 + 4u;
  TF_ROUNDS_A(x0,x1) x0 += k2; x1 += k0 + 5u;
  o0 = x0; o1 = x1;
}

// JAX partitionable random_bits (32-bit): xor-fold of threefry(key, (0, idx)).
// Then jax.random.normal: u = max(lo, u01*2 + lo), lo = -(1-2^-24);
// result = sqrt(2) * erfinv(u) with XLA/chlo's Giles f32 polynomial.
__device__ __forceinline__ float jax_normal32(uint32_t k0, uint32_t k1, uint32_t idx) {
  uint32_t o0, o1;
  threefry2x32(k0, k1, 0u, idx, o0, o1);
  uint32_t bits = o0 ^ o1;
  float u01 = __uint_as_float((bits >> 9) | 0x3f800000u) - 1.0f;  // exact subtract
  float u = __fadd_rn(__fmul_rn(u01, 2.0f), -0.99999994f);
  u = fmaxf(u, -0.99999994f);
  float xx = __fmul_rn(u, u);
  float w = -log1pf(-xx);
  float p;
  if (w < 5.0f) {
    w = __fadd_rn(w, -2.5f);
    p =                2.81022636e-08f;
    p = __fadd_rn( 3.43273939e-07f, __fmul_rn(p, w));
    p = __fadd_rn(-3.5233877e-06f,  __fmul_rn(p, w));
    p = __fadd_rn(-4.39150654e-06f, __fmul_rn(p, w));
    p = __fadd_rn( 0.00021858087f,  __fmul_rn(p, w));
    p = __fadd_rn(-0.00125372503f,  __fmul_rn(p, w));
    p = __fadd_rn(-0.00417768164f,  __fmul_rn(p, w));
    p = __fadd_rn( 0.246640727f,    __fmul_rn(p, w));
    p = __fadd_rn( 1.50140941f,     __fmul_rn(p, w));
  } else {
    w = __fadd_rn(__fsqrt_rn(w), -3.0f);
    p =               -0.000200214257f;
    p = __fadd_rn( 0.000100950558f, __fmul_rn(p, w));
    p = __fadd_rn( 0.00134934322f,  __fmul_rn(p, w));
    p = __fadd_rn(-0.00367342844f,  __fmul_rn(p, w));
    p = __fadd_rn( 0.00573950773f,  __fmul_rn(p, w));
    p = __fadd_rn(-0.0076224613f,   __fmul_rn(p, w));
    p = __fadd_rn( 0.00943887047f,  __fmul_rn(p, w));
    p = __fadd_rn( 1.00167406f,     __fmul_rn(p, w));
    p = __fadd_rn( 2.83297682f,     __fmul_rn(p, w));
  }
  return __fmul_rn(1.41421356f, __fmul_rn(p, u));   // sqrt(2) * (p*x)
}

__device__ __forceinline__ float softplus_ref(float x) {
  float l = log1pf(expf(fminf(x, 20.0f)));
  return (x > 20.0f) ? x : l;
}

// One block = one (s, 64-point tile). Activations live transposed in LDS.
__global__ __launch_bounds__(256, 2)
void vsiren_kernel(const float* __restrict__ X,
                   const float* __restrict__ mu0, const float* __restrict__ ls0,
                   const float* __restrict__ mu1, const float* __restrict__ ls1,
                   const float* __restrict__ mu2, const float* __restrict__ ls2,
                   const float* __restrict__ mu3, const float* __restrict__ ls3,
                   const float* __restrict__ mu4, const float* __restrict__ ls4,
                   float* __restrict__ out, Keys keys)
{
  __shared__ float hT[256][NTILE];   // 64 KB: hT[feature][row]
  __shared__ float s2b[32][128];     // 16 KB: softplus(ls)^2 chunk; X-tile scratch early

  const int tid = threadIdx.x;
  const uint32_t bid = blockIdx.x;
  // XCD swizzle: each XCD walks blocks of one s at a time -> weights stay in its L2
  const uint32_t swz = (bid & 7u) * (NBLOCKS / 8) + (bid >> 3);
  const int s  = (int)(swz >> 7);
  const int n0 = (int)(swz & 127u) * NTILE;

  if (tid < 2 * NTILE) s2b[0][tid] = X[(size_t)(s * NPTS + n0) * 2 + tid];
  __syncthreads();

  // ---- posenc: h0[f] = {cos,sin}(pi * x_d * w_k), f = (sin?128:0) + d*64 + k ----
  {
    const int r = tid & 63, q = tid >> 6;      // q: 0=cos x0, 1=cos x1, 2=sin x0, 3=sin x1
    const float xv = s2b[0][r * 2 + (q & 1)];
    const float delta = 6.93147182464599609375f / 63.0f;  // f32(log 1024)/63, folded exactly
    #pragma unroll 8
    for (int k = 0; k < 64; ++k) {
      float w = expf(__fmul_rn((float)k, delta));
      float arg = __fmul_rn(3.14159274101257324f, __fmul_rn(xv, w));
      hT[q * 64 + k][r] = (q < 2) ? cosf(arg) : sinf(arg);
    }
  }
  __syncthreads();

  const float* mus[4] = {mu0, mu1, mu2, mu3};
  const float* lss[4] = {ls0, ls1, ls2, ls3};
  const int tc = tid & 15, tr = tid >> 4;      // thread tile: 4 rows x 8 cols

  float zh[2][4][8];

  for (int l = 0; l < 4; ++l) {
    const float* __restrict__ mu = mus[l] + (size_t)s * (257 * 256);
    const float* __restrict__ ls = lss[l] + (size_t)s * (257 * 256);
    const uint32_t lk0 = keys.k0[l], lk1 = keys.k1[l];

    #pragma unroll
    for (int cp = 0; cp < 2; ++cp) {
      const int colbase = cp * 128;
      float am[4][8], av[4][8];
      #pragma unroll
      for (int i = 0; i < 4; ++i)
        #pragma unroll
        for (int j = 0; j < 8; ++j) { am[i][j] = 0.f; av[i][j] = 0.f; }

      for (int ch = 0; ch < 8; ++ch) {
        __syncthreads();
        // stage softplus(ls)^2 for k-rows [ch*32, ch*32+32) x cols [colbase, colbase+128)
        #pragma unroll
        for (int i = 0; i < 16; ++i) {
          int e = tid + i * 256;
          int kr = e >> 7, cc = e & 127;
          float lv = ls[(size_t)(ch * 32 + kr) * 256 + colbase + cc];
          float sp = softplus_ref(lv);
          s2b[kr][cc] = __fmul_rn(sp, sp);
        }
        __syncthreads();

        #pragma unroll 4
        for (int kk = 0; kk < 32; ++kk) {
          const int k = ch * 32 + kk;
          const float4 a  = *(const float4*)&hT[k][tr * 4];
          const float* wr = mu + (size_t)k * 256 + colbase + tc * 8;
          const float4 w0 = *(const float4*)(wr);
          const float4 w1 = *(const float4*)(wr + 4);
          const float4 q0 = *(const float4*)&s2b[kk][tc * 8];
          const float4 q1 = *(const float4*)&s2b[kk][tc * 8 + 4];
          const float ar[4] = {a.x, a.y, a.z, a.w};
          const float wm[8] = {w0.x, w0.y, w0.z, w0.w, w1.x, w1.y, w1.z, w1.w};
          const float ws[8] = {q0.x, q0.y, q0.z, q0.w, q1.x, q1.y, q1.z, q1.w};
          #pragma unroll
          for (int rr = 0; rr < 4; ++rr) {
            const float hv = ar[rr];
            const float h2 = __fmul_rn(hv, hv);
            #pragma unroll
            for (int c = 0; c < 8; ++c) {
              am[rr][c] = fmaf(hv, wm[c], am[rr][c]);
              av[rr][c] = fmaf(h2, ws[c], av[rr][c]);
            }
          }
        }
      }

      // epilogue for this col-pass: bias, variance, noise, activation (held in regs)
      float mub[8], vb[8];
      #pragma unroll
      for (int c = 0; c < 8; ++c) {
        int col = colbase + tc * 8 + c;
        mub[c] = mu[(size_t)256 * 256 + col];
        float sp = softplus_ref(ls[(size_t)256 * 256 + col]);
        vb[c] = __fmul_rn(sp, sp);
      }
      #pragma unroll
      for (int rr = 0; rr < 4; ++rr) {
        const int n = n0 + tr * 4 + rr;
        #pragma unroll
        for (int c = 0; c < 8; ++c) {
          const int col = colbase + tc * 8 + c;
          float m   = __fadd_rn(am[rr][c], mub[c]);
          float var = __fadd_rn(__fadd_rn(av[rr][c], vb[c]), 1e-14f);
          float sv  = __fsqrt_rn(var);
          uint32_t idx = ((uint32_t)(s * NPTS + n)) * 256u + (uint32_t)col;
          float nz = jax_normal32(lk0, lk1, idx);
          float z  = __fadd_rn(m, __fmul_rn(sv, nz));
          zh[cp][rr][c] = sinf(__fmul_rn(30.0f, z));
        }
      }
    } // cp

    __syncthreads();   // all hT reads for this layer done
    #pragma unroll
    for (int cp = 0; cp < 2; ++cp)
      #pragma unroll
      for (int c = 0; c < 8; ++c) {
        const int col = cp * 128 + tc * 8 + c;
        float4 v = make_float4(zh[cp][0][c], zh[cp][1][c], zh[cp][2][c], zh[cp][3][c]);
        *(float4*)&hT[col][tr * 4] = v;
      }
    __syncthreads();
  } // layer

  // ---- layer 4: 256 -> 3, last=True (no sin) ----
  {
    const float* __restrict__ mu = mu4 + (size_t)s * (257 * 3);
    const float* __restrict__ ls = ls4 + (size_t)s * (257 * 3);
    const int r = tid >> 2, o = tid & 3;
    if (o < 3) {
      float am = 0.f, av2 = 0.f;
      for (int k = 0; k < 256; ++k) {
        float hv  = hT[k][r];
        float wmv = mu[k * 3 + o];
        float sp  = softplus_ref(ls[k * 3 + o]);
        am  = fmaf(hv, wmv, am);
        av2 = fmaf(__fmul_rn(hv, hv), __fmul_rn(sp, sp), av2);
      }
      float m   = __fadd_rn(am, mu[256 * 3 + o]);
      float spb = softplus_ref(ls[256 * 3 + o]);
      float var = __fadd_rn(__fadd_rn(av2, __fmul_rn(spb, spb)), 1e-14f);
      float sv  = __fsqrt_rn(var);
      const int n = n0 + r;
      uint32_t idx = ((uint32_t)(s * NPTS + n)) * 3u + (uint32_t)o;
      float nz = jax_normal32(keys.k0[4], keys.k1[4], idx);
      out[(size_t)(s * NPTS + n) * 3 + o] = __fadd_rn(m, __fmul_rn(sv, nz));
    }
  }
}

extern "C" void kernel_launch(void* const* d_in, const int* in_sizes, int n_in,
                              void* d_out, int out_size, void* d_ws, size_t ws_size,
                              hipStream_t stream) {
  (void)in_sizes; (void)n_in; (void)d_ws; (void)ws_size; (void)out_size;
  const float* X   = (const float*)d_in[0];
  const float* mu0 = (const float*)d_in[1];
  const float* ls0 = (const float*)d_in[2];
  const float* mu1 = (const float*)d_in[3];
  const float* ls1 = (const float*)d_in[4];
  const float* mu2 = (const float*)d_in[5];
  const float* ls2 = (const float*)d_in[6];
  const float* mu3 = (const float*)d_in[7];
  const float* ls3 = (const float*)d_in[8];
  const float* mu4 = (const float*)d_in[9];
  const float* ls4 = (const float*)d_in[10];

  // jax.random.split(key(42), 5) with threefry_partitionable (fold-like):
  // keys[l] = threefry2x32((0,42), (0, l))
  Keys keys;
  for (int l = 0; l < 5; ++l) {
    uint32_t o0, o1;
    threefry2x32(0u, 42u, 0u, (uint32_t)l, o0, o1);
    keys.k0[l] = o0; keys.k1[l] = o1;
  }

  vsiren_kernel<<<dim3(NBLOCKS), dim3(256), 0, stream>>>(
      X, mu0, ls0, mu1, ls1, mu2, ls2, mu3, ls3, mu4, ls4,
      (float*)d_out, keys);
}